// Round 15
// baseline (19.142 us; speedup 1.0000x reference)
//
#include <hip/hip_runtime.h>
#include <math.h>

#define B_ 32768
#define E_ 256
#define S_ 1024
#define EPS_COS 1e-8f
#define EPS_NORM 1e-12f

typedef float fx4 __attribute__((ext_vector_type(4)));

// ---------------- kernel 1: rows (1-wave blocks, ILP-4, no barriers) -------
// 2048 blocks x 64 threads (1 wave). 16-lane group g owns rows
// 16b+4g .. 16b+4g+3 in one straight-line body: 16 loads in flight,
// 4 independent butterfly chains, NT stores. Block reduce = 2 extra
// shfl levels across the wave (no LDS, no __syncthreads).
// PB[b] = sum over the block's 16 rows; speaker = PB[2k]+PB[2k+1].
__global__ __launch_bounds__(64) void rows_kernel(
        const float* __restrict__ x, const int* __restrict__ tgt,
        float* __restrict__ outN, float* __restrict__ outL,
        float* __restrict__ rowsum, float* __restrict__ sqsum,
        float* __restrict__ PBsum, int* __restrict__ PBtgt) {
    int tid = threadIdx.x;
    int g   = tid >> 4;                 // 4 groups of 16 lanes
    int li  = tid & 15;
    int r0  = blockIdx.x * 16 + g * 4;  // group's first row

    if (blockIdx.x == 0 && tid == 0) outL[0] = 0.f;

    const fx4* __restrict__ xr = (const fx4*)(x + (size_t)r0 * E_);
    fx4* __restrict__ orow = (fx4*)(outN + (size_t)r0 * E_);

    // 16 loads in flight (4 rows x 4 fx4); row stride = 64 fx4
    fx4 a0 = xr[li];       fx4 a1 = xr[li + 16];
    fx4 a2 = xr[li + 32];  fx4 a3 = xr[li + 48];
    fx4 b0 = xr[li + 64];  fx4 b1 = xr[li + 80];
    fx4 b2 = xr[li + 96];  fx4 b3 = xr[li + 112];
    fx4 c0 = xr[li + 128]; fx4 c1 = xr[li + 144];
    fx4 c2 = xr[li + 160]; fx4 c3 = xr[li + 176];
    fx4 d0 = xr[li + 192]; fx4 d1 = xr[li + 208];
    fx4 d2 = xr[li + 224]; fx4 d3 = xr[li + 240];

    // ---- row A (stores overlap later rows' load returns) ----
    float sumA = (a0.x+a0.y+a0.z+a0.w)+(a1.x+a1.y+a1.z+a1.w)
               + (a2.x+a2.y+a2.z+a2.w)+(a3.x+a3.y+a3.z+a3.w);
    float sqA  = (a0.x*a0.x+a0.y*a0.y+a0.z*a0.z+a0.w*a0.w)
               + (a1.x*a1.x+a1.y*a1.y+a1.z*a1.z+a1.w*a1.w)
               + (a2.x*a2.x+a2.y*a2.y+a2.z*a2.z+a2.w*a2.w)
               + (a3.x*a3.x+a3.y*a3.y+a3.z*a3.z+a3.w*a3.w);
    #pragma unroll
    for (int o = 8; o >= 1; o >>= 1) {
        sumA += __shfl_xor(sumA, o, 64);
        sqA  += __shfl_xor(sqA,  o, 64);
    }
    float rnA = 1.0f / fmaxf(sqrtf(sqA), EPS_NORM);
    __builtin_nontemporal_store(a0 * rnA, &orow[li]);
    __builtin_nontemporal_store(a1 * rnA, &orow[li + 16]);
    __builtin_nontemporal_store(a2 * rnA, &orow[li + 32]);
    __builtin_nontemporal_store(a3 * rnA, &orow[li + 48]);

    // ---- row B ----
    float sumB = (b0.x+b0.y+b0.z+b0.w)+(b1.x+b1.y+b1.z+b1.w)
               + (b2.x+b2.y+b2.z+b2.w)+(b3.x+b3.y+b3.z+b3.w);
    float sqB  = (b0.x*b0.x+b0.y*b0.y+b0.z*b0.z+b0.w*b0.w)
               + (b1.x*b1.x+b1.y*b1.y+b1.z*b1.z+b1.w*b1.w)
               + (b2.x*b2.x+b2.y*b2.y+b2.z*b2.z+b2.w*b2.w)
               + (b3.x*b3.x+b3.y*b3.y+b3.z*b3.z+b3.w*b3.w);
    #pragma unroll
    for (int o = 8; o >= 1; o >>= 1) {
        sumB += __shfl_xor(sumB, o, 64);
        sqB  += __shfl_xor(sqB,  o, 64);
    }
    float rnB = 1.0f / fmaxf(sqrtf(sqB), EPS_NORM);
    __builtin_nontemporal_store(b0 * rnB, &orow[li + 64]);
    __builtin_nontemporal_store(b1 * rnB, &orow[li + 80]);
    __builtin_nontemporal_store(b2 * rnB, &orow[li + 96]);
    __builtin_nontemporal_store(b3 * rnB, &orow[li + 112]);

    // ---- row C ----
    float sumC = (c0.x+c0.y+c0.z+c0.w)+(c1.x+c1.y+c1.z+c1.w)
               + (c2.x+c2.y+c2.z+c2.w)+(c3.x+c3.y+c3.z+c3.w);
    float sqC  = (c0.x*c0.x+c0.y*c0.y+c0.z*c0.z+c0.w*c0.w)
               + (c1.x*c1.x+c1.y*c1.y+c1.z*c1.z+c1.w*c1.w)
               + (c2.x*c2.x+c2.y*c2.y+c2.z*c2.z+c2.w*c2.w)
               + (c3.x*c3.x+c3.y*c3.y+c3.z*c3.z+c3.w*c3.w);
    #pragma unroll
    for (int o = 8; o >= 1; o >>= 1) {
        sumC += __shfl_xor(sumC, o, 64);
        sqC  += __shfl_xor(sqC,  o, 64);
    }
    float rnC = 1.0f / fmaxf(sqrtf(sqC), EPS_NORM);
    __builtin_nontemporal_store(c0 * rnC, &orow[li + 128]);
    __builtin_nontemporal_store(c1 * rnC, &orow[li + 144]);
    __builtin_nontemporal_store(c2 * rnC, &orow[li + 160]);
    __builtin_nontemporal_store(c3 * rnC, &orow[li + 176]);

    // ---- row D ----
    float sumD = (d0.x+d0.y+d0.z+d0.w)+(d1.x+d1.y+d1.z+d1.w)
               + (d2.x+d2.y+d2.z+d2.w)+(d3.x+d3.y+d3.z+d3.w);
    float sqD  = (d0.x*d0.x+d0.y*d0.y+d0.z*d0.z+d0.w*d0.w)
               + (d1.x*d1.x+d1.y*d1.y+d1.z*d1.z+d1.w*d1.w)
               + (d2.x*d2.x+d2.y*d2.y+d2.z*d2.z+d2.w*d2.w)
               + (d3.x*d3.x+d3.y*d3.y+d3.z*d3.z+d3.w*d3.w);
    #pragma unroll
    for (int o = 8; o >= 1; o >>= 1) {
        sumD += __shfl_xor(sumD, o, 64);
        sqD  += __shfl_xor(sqD,  o, 64);
    }
    float rnD = 1.0f / fmaxf(sqrtf(sqD), EPS_NORM);
    __builtin_nontemporal_store(d0 * rnD, &orow[li + 192]);
    __builtin_nontemporal_store(d1 * rnD, &orow[li + 208]);
    __builtin_nontemporal_store(d2 * rnD, &orow[li + 224]);
    __builtin_nontemporal_store(d3 * rnD, &orow[li + 240]);

    // ---- per-row scalar outputs ----
    if (li == 0) {
        rowsum[r0]     = sumA;  sqsum[r0]     = sqA;
        rowsum[r0 + 1] = sumB;  sqsum[r0 + 1] = sqB;
        rowsum[r0 + 2] = sumC;  sqsum[r0 + 2] = sqC;
        rowsum[r0 + 3] = sumD;  sqsum[r0 + 3] = sqD;
    }

    // ---- block (wave) reduce: every lane has its group's 4 sums ----
    int4 t4 = *(const int4*)(tgt + r0);     // same addr per group: broadcast
    int tmn = min(min(t4.x, t4.y), min(t4.z, t4.w));
    int tmx = max(max(t4.x, t4.y), max(t4.z, t4.w));
    float gs = sumA + sumB + sumC + sumD;
    gs  += __shfl_xor(gs, 16, 64);
    gs  += __shfl_xor(gs, 32, 64);
    tmn  = min(tmn, __shfl_xor(tmn, 16, 64));
    tmn  = min(tmn, __shfl_xor(tmn, 32, 64));
    tmx  = max(tmx, __shfl_xor(tmx, 16, 64));
    tmx  = max(tmx, __shfl_xor(tmx, 32, 64));
    if (tid == 0) {
        PBsum[blockIdx.x] = gs;
        PBtgt[blockIdx.x] = (tmn == tmx) ? tmn : -1;
    }
}

// ---------------- kernel 2: loss -------------------------------------------
// 128 blocks x 256 threads; block handles rows [256b, 256b+256).
// Fast path: PBtgt[i]==i>>1 for all i  =>  s[k]=PBsum[2k]+PBsum[2k+1], n=32.
// Slow path: rebuild full histogram from rowsum/tgt with LDS atomics.
__global__ __launch_bounds__(256) void loss_kernel(
        const float* __restrict__ rowsum, const float* __restrict__ sqsum,
        const int* __restrict__ tgt,
        const float* __restrict__ PBsum, const int* __restrict__ PBtgt,
        const float* __restrict__ wP, const float* __restrict__ bP,
        float* __restrict__ outL) {
    __shared__ float s_h[S_];
    __shared__ float c_h[S_];
    __shared__ int   ired[256];
    __shared__ float fred[256];

    int tid = threadIdx.x;

    int packed = 0;     // (npos<<16) | nneg
    int bad = 0;
    #pragma unroll
    for (int j = 0; j < 4; ++j) {
        int k = tid * 4 + j;
        float sk = PBsum[2*k] + PBsum[2*k+1];
        int ok = (PBtgt[2*k] == k) & (PBtgt[2*k+1] == k);
        bad |= !ok;
        s_h[k] = sk;
        c_h[k] = 32.0f;
        float cv = sk * (1.0f / 32.0f);
        if (fabsf(cv) * 16.0f >= EPS_COS) packed += (cv > 0.f) ? (1 << 16) : 1;
    }
    ired[tid] = packed | (bad ? (1 << 15) : 0);   // bit15 = bad flag
    __syncthreads();
    #pragma unroll
    for (int st = 128; st > 0; st >>= 1) {
        if (tid < st) {
            int a = ired[tid], b = ired[tid + st];
            ired[tid] = ((a + b) & ~(1 << 15)) | ((a | b) & (1 << 15));
        }
        __syncthreads();
    }
    int agg  = ired[0];
    int slow = (agg >> 15) & 1;
    int npos = (agg >> 16) & 0xFFFF;
    int nneg = agg & 0x7FFF;

    if (slow) {   // ---- general path: rebuild histogram from rows ----
        __syncthreads();
        s_h[tid] = 0.f; s_h[tid + 256] = 0.f; s_h[tid + 512] = 0.f; s_h[tid + 768] = 0.f;
        c_h[tid] = 0.f; c_h[tid + 256] = 0.f; c_h[tid + 512] = 0.f; c_h[tid + 768] = 0.f;
        __syncthreads();
        for (int i = tid; i < B_; i += 256) {
            int t = tgt[i];
            atomicAdd(&s_h[t], rowsum[i]);
            atomicAdd(&c_h[t], 1.0f);
        }
        __syncthreads();
        packed = 0;
        #pragma unroll
        for (int j = 0; j < 4; ++j) {
            int k = tid * 4 + j;
            float cv = s_h[k] / c_h[k];
            if (fabsf(cv) * 16.0f >= EPS_COS) packed += (cv > 0.f) ? (1 << 16) : 1;
        }
        ired[tid] = packed;
        __syncthreads();
        #pragma unroll
        for (int st = 128; st > 0; st >>= 1) {
            if (tid < st) ired[tid] += ired[tid + st];
            __syncthreads();
        }
        npos = ired[0] >> 16;
        nneg = ired[0] & 0xFFFF;
    }

    // ---- per-row loss ----
    int i = blockIdx.x * 256 + tid;
    float w  = wP[0], b = bP[0];
    float wr = fmaxf(w, 0.f);

    int   t  = tgt[i];
    float rs = rowsum[i], sq = sqsum[i];
    float sj = s_h[t], nj = c_h[t];

    float nem = fmaxf(sqrtf(sq), EPS_COS);

    float dot = (sj * rs - sq) / nj;
    float nc  = sqrtf((float)E_ * sj * sj - 2.f * sj * rs + sq) / nj;
    float self_cos = dot / (nem * fmaxf(nc, EPS_COS));
    float self_sim = wr * self_cos + b;

    float A  = wr * rs / (nem * 16.0f);
    float xp =  A + b, xm = -A + b, xz = b;

    float ct = sj / nj;
    int np = npos, nm = nneg, nz = S_ - npos - nneg;
    if (fabsf(ct) * 16.0f >= EPS_COS) { if (ct > 0.f) np--; else nm--; }
    else nz--;

    float m = self_sim;
    if (np > 0) m = fmaxf(m, xp);
    if (nm > 0) m = fmaxf(m, xm);
    if (nz > 0) m = fmaxf(m, xz);
    float ssum = expf(self_sim - m)
               + (float)np * expf(xp - m)
               + (float)nm * expf(xm - m)
               + (float)nz * expf(xz - m);
    float contrib = m + logf(ssum) - self_sim;

    fred[tid] = contrib;
    __syncthreads();
    #pragma unroll
    for (int st = 128; st > 0; st >>= 1) {
        if (tid < st) fred[tid] += fred[tid + st];
        __syncthreads();
    }
    if (tid == 0) atomicAdd(outL, fred[0]);
}

extern "C" void kernel_launch(void* const* d_in, const int* in_sizes, int n_in,
                              void* d_out, int out_size, void* d_ws, size_t ws_size,
                              hipStream_t stream) {
    const float* inputs  = (const float*)d_in[0];
    const int*   targets = (const int*)d_in[1];
    const float* wP      = (const float*)d_in[2];
    const float* bP      = (const float*)d_in[3];
    float* outN = (float*)d_out;                    // [B,E] normalized
    float* outL = (float*)d_out + (size_t)B_ * E_;  // [1] loss

    float* wsf    = (float*)d_ws;
    float* rowsum = wsf;                     // B
    float* sqsum  = wsf + B_;                // B
    float* PBsum  = wsf + 2 * B_;            // 2048
    int*   PBtgt  = (int*)(PBsum + 2048);    // 2048

    rows_kernel<<<B_ / 16, 64, 0, stream>>>(inputs, targets, outN, outL,
                                            rowsum, sqsum, PBsum, PBtgt);
    loss_kernel<<<B_ / 256, 256, 0, stream>>>(rowsum, sqsum, targets,
                                              PBsum, PBtgt, wP, bP, outL);
}